// Round 2
// baseline (1489.975 us; speedup 1.0000x reference)
//
#include <hip/hip_runtime.h>

// Sparsemax attention: B=8, L=1024, S=1024, H=16, E=64, D=64, fp32 in/out.
// r11 = r9 (staged-K, coalesced, VGPR=64) + CAP 192->112: lists 48KB->28KB,
// total LDS 49920B -> 3 blocks/CU (24 waves, was 16). launch_bounds kept at
// (512,4) -- forcing 6 waves/EU in r10 spilled (VGPR 40 + 590MB scratch WB).
// Also keeps r10's 2-wide A*V gather for ILP.

typedef _Float16 f16x8 __attribute__((ext_vector_type(8)));
typedef float    f32x4 __attribute__((ext_vector_type(4)));

constexpr int kB = 8, kL = 1024, kS = 1024, kH = 16, kE = 64, kD = 64;
constexpr int LT   = 32;          // L rows per block (2 query-groups of 16)
constexpr int JT   = 128;         // S cols per staged K tile
constexpr int CAP  = 112;         // candidate capacity per row (mean ~36)
constexpr int KMAX = CAP / 16;    // Newton regs per lane (16 lanes per row)

__device__ __forceinline__ float pk2(float a, float b) {
  auto h = __builtin_amdgcn_cvt_pkrtz(a, b);
  return __builtin_bit_cast(float, h);
}

__global__ __launch_bounds__(512, 4)
void sparsemax_attn(const float* __restrict__ Q, const float* __restrict__ K,
                    const float* __restrict__ V, float* __restrict__ O) {
  __shared__ float4 Ksh[JT * 8];       // 16 KB fp16 K tile, swizzled slot^(row&7)
  __shared__ float4 Qsh[LT * 8];       //  4 KB fp16 Q tile (scale folded)
  __shared__ float2 lists[LT * CAP];   // 28 KB (z, j-as-float)
  __shared__ int    cnt_s[LT];
  __shared__ float  rmax_s[LT][4];
  __shared__ float  tau_s[LT];

  const int t = threadIdx.x, lane = t & 63, w = t >> 6;
  const int qg = w >> 2, jg = w & 3;       // query-group, j-group
  const int li = lane & 15, g = lane >> 4;
  const int myrow = qg * 16 + li;          // the ONE output row this lane serves

  // XCD-aware remap: round-robin id%8 -> XCD; same-XCD blocks share few bh.
  const int id  = blockIdx.x;              // 4096 blocks
  const int xcd = id & 7, kk = id >> 3;
  const int bh  = xcd * 16 + (kk >> 5);    // 16 bh per XCD, slow-varying
  const int b   = bh >> 4, h = bh & 15;
  const int l0  = (kk & 31) * LT;

  const float* Kbh = K + ((size_t)b * kS * kH + h) * kE;
  const float* Vb  = V + ((size_t)b * kS * kH + h) * kD;

  if (t < LT) cnt_s[t] = 0;
  if (t < 256) {  // stage Q: 32 rows x 8 slots of 8 halfs
    const int jj = t >> 3, e8 = t & 7;
    const float4* qp =
        (const float4*)(Q + (((size_t)(b * kL + l0 + jj)) * kH + h) * kE + e8 * 8);
    float4 q0 = qp[0], q1 = qp[1];
    q0.x *= .125f; q0.y *= .125f; q0.z *= .125f; q0.w *= .125f;
    q1.x *= .125f; q1.y *= .125f; q1.z *= .125f; q1.w *= .125f;
    Qsh[jj * 8 + (e8 ^ (jj & 7))] =
        make_float4(pk2(q0.x, q0.y), pk2(q0.z, q0.w), pk2(q1.x, q1.y), pk2(q1.z, q1.w));
  }

  float runl = -1e30f;    // per-lane cumulative max over seen scores of myrow
  f16x8 b0, b1;           // cached Q fragments (B operand)

  for (int jt = 0; jt < kS / JT; ++jt) {
    __syncthreads();
    // stage K tile: 128 rows x 64 halfs; 2 units per thread
#pragma unroll
    for (int i = 0; i < 2; ++i) {
      const int idx = t + 512 * i, jj = idx >> 3, e8 = idx & 7;
      const float4* kp =
          (const float4*)(Kbh + (size_t)(jt * JT + jj) * (kH * kE) + e8 * 8);
      const float4 c0 = kp[0], c1 = kp[1];
      Ksh[jj * 8 + (e8 ^ (jj & 7))] =
          make_float4(pk2(c0.x, c0.y), pk2(c0.z, c0.w), pk2(c1.x, c1.y), pk2(c1.z, c1.w));
    }
    __syncthreads();
    if (jt == 0) {  // B-frags: Q[row = myrow][k-chunks g, 4+g] (k-contiguous)
      b0 = __builtin_bit_cast(f16x8, Qsh[myrow * 8 + ((0 + g) ^ (myrow & 7))]);
      b1 = __builtin_bit_cast(f16x8, Qsh[myrow * 8 + ((4 + g) ^ (myrow & 7))]);
    }

    f32x4 acc[2];
    acc[0] = f32x4{0.f, 0.f, 0.f, 0.f};
    acc[1] = f32x4{0.f, 0.f, 0.f, 0.f};
#pragma unroll
    for (int ct = 0; ct < 2; ++ct) {  // A = K rows jl (m dim = j)
      const int jl = jg * 32 + ct * 16 + li;
      const f16x8 a0 = __builtin_bit_cast(f16x8, Ksh[jl * 8 + ((0 + g) ^ (jl & 7))]);
      const f16x8 a1 = __builtin_bit_cast(f16x8, Ksh[jl * 8 + ((4 + g) ^ (jl & 7))]);
      acc[ct] = __builtin_amdgcn_mfma_f32_16x16x32_f16(a0, b0, acc[ct], 0, 0, 0);
      acc[ct] = __builtin_amdgcn_mfma_f32_16x16x32_f16(a1, b1, acc[ct], 0, 0, 0);
    }
    // D[j = jt*128 + jg*32 + ct*16 + g*4 + reg][query = myrow]

    // ---- filter: per-lane max tree + 2-shuffle g-reduce ----
    const float m01 = fmaxf(fmaxf(acc[0][0], acc[0][1]), fmaxf(acc[0][2], acc[0][3]));
    const float m23 = fmaxf(fmaxf(acc[1][0], acc[1][1]), fmaxf(acc[1][2], acc[1][3]));
    runl = fmaxf(runl, fmaxf(m01, m23));
    float mr = fmaxf(runl, __shfl_xor(runl, 16));
    mr = fmaxf(mr, __shfl_xor(mr, 32));
    const float thr = mr - 1.0f;  // <= rowmax-1 <= tau*: superset filter
    const int jbase = jt * JT + jg * 32 + g * 4;
#pragma unroll
    for (int ct = 0; ct < 2; ++ct)
#pragma unroll
      for (int r = 0; r < 4; ++r) {
        const float z = acc[ct][r];
        if (z > thr) {
          const int pos = atomicAdd(&cnt_s[myrow], 1);
          if (pos < CAP)
            lists[myrow * CAP + pos] =
                make_float2(z, __int_as_float(jbase + ct * 16 + r));
        }
      }
  }
  {
    float mr = fmaxf(runl, __shfl_xor(runl, 16));
    mr = fmaxf(mr, __shfl_xor(mr, 32));
    if (lane < 16) rmax_s[myrow][jg] = mr;
  }
  __syncthreads();

  // ---- Newton: wave w owns rows w*4..+3; row w*4+g, 16 lanes each ----
  const int q0 = w * 4;
  {
    const int row = q0 + g;
    const int n   = cnt_s[row];
    const int nc  = min(n, CAP);
    float zr[KMAX];
#pragma unroll
    for (int k = 0; k < KMAX; ++k) {
      const int i = li + 16 * k;
      zr[k] = (i < nc) ? lists[row * CAP + i].x : -1e30f;
    }
    const float M =
        fmaxf(fmaxf(rmax_s[row][0], rmax_s[row][1]), fmaxf(rmax_s[row][2], rmax_s[row][3]));
    float t0 = M - 1.0f;
    for (int it = 0; it < 14; ++it) {
      float s = 0.f, c = 0.f;
#pragma unroll
      for (int k = 0; k < KMAX; ++k) {
        const float d = zr[k] - t0;
        if (d > 0.f) { s += d; c += 1.f; }
      }
      s += __shfl_xor(s, 1); c += __shfl_xor(c, 1);
      s += __shfl_xor(s, 2); c += __shfl_xor(c, 2);
      s += __shfl_xor(s, 4); c += __shfl_xor(c, 4);
      s += __shfl_xor(s, 8); c += __shfl_xor(c, 8);
      const float delta = (s - 1.0f) / fmaxf(c, 1.f);
      t0 += fmaxf(delta, 0.f);
      if (__all(delta <= 1e-6f)) break;
    }
    if (li == 0) tau_s[row] = t0;
  }

  // ---- sparse A*V: 8 candidates concurrent (2 per g), float4 over dims ----
#pragma unroll 1
  for (int r4 = 0; r4 < 4; ++r4) {
    const int row = q0 + r4;
    const int n   = cnt_s[row];
    const size_t obase = (((size_t)(b * kL + l0 + row)) * kH + h) * kD;
    if (n <= CAP) {
      const float tau = tau_s[row];
      const int nc = n;  // n >= 1 always (row max passes its own filter)
      f32x4 o4 = {0.f, 0.f, 0.f, 0.f};
      for (int i = g; i < nc; i += 8) {
        const int   i2 = i + 4;
        const bool  ok2 = (i2 < nc);
        const float2 e1 = lists[row * CAP + i];
        const float2 e2 = lists[row * CAP + (ok2 ? i2 : i)];
        const float  p1 = fmaxf(e1.x - tau, 0.f);
        const float  p2 = ok2 ? fmaxf(e2.x - tau, 0.f) : 0.f;
        const float4 v1 =
            ((const float4*)(Vb + (size_t)__float_as_int(e1.y) * (kH * kD)))[li];
        const float4 v2 =
            ((const float4*)(Vb + (size_t)__float_as_int(e2.y) * (kH * kD)))[li];
        o4.x = fmaf(p1, v1.x, fmaf(p2, v2.x, o4.x));
        o4.y = fmaf(p1, v1.y, fmaf(p2, v2.y, o4.y));
        o4.z = fmaf(p1, v1.z, fmaf(p2, v2.z, o4.z));
        o4.w = fmaf(p1, v1.w, fmaf(p2, v2.w, o4.w));
      }
      o4.x += __shfl_xor(o4.x, 16); o4.y += __shfl_xor(o4.y, 16);
      o4.z += __shfl_xor(o4.z, 16); o4.w += __shfl_xor(o4.w, 16);
      o4.x += __shfl_xor(o4.x, 32); o4.y += __shfl_xor(o4.y, 32);
      o4.z += __shfl_xor(o4.z, 32); o4.w += __shfl_xor(o4.w, 32);
      if (lane < 16)
        ((float4*)(O + obase))[li] = make_float4(o4.x, o4.y, o4.z, o4.w);
    } else {
      // ---- cold exact fallback (list overflow): dense recompute ----
      float scr2[16];
      for (int cc = 0; cc < 16; ++cc) {
        const int j = lane + 64 * cc;
        const float* kr = Kbh + (size_t)j * (kH * kE);
        float zz = 0.f;
        for (int e8 = 0; e8 < 8; ++e8) {
          const f16x8 qh = __builtin_bit_cast(f16x8, Qsh[row * 8 + (e8 ^ (row & 7))]);
          const float4* kp = (const float4*)(kr + e8 * 8);
          const float4 c0 = kp[0], c1 = kp[1];
          zz += (float)qh[0] * c0.x + (float)qh[1] * c0.y + (float)qh[2] * c0.z +
                (float)qh[3] * c0.w + (float)qh[4] * c1.x + (float)qh[5] * c1.y +
                (float)qh[6] * c1.z + (float)qh[7] * c1.w;
        }
        scr2[cc] = zz;
      }
      const float M2 =
          fmaxf(fmaxf(rmax_s[row][0], rmax_s[row][1]), fmaxf(rmax_s[row][2], rmax_s[row][3]));
      float t0 = M2 - 1.0f;
      for (int it = 0; it < 48; ++it) {
        float s = 0.f, c = 0.f;
        for (int cc = 0; cc < 16; ++cc) {
          const float d = scr2[cc] - t0;
          if (d > 0.f) { s += d; c += 1.f; }
        }
        for (int off = 32; off; off >>= 1) { s += __shfl_xor(s, off); c += __shfl_xor(c, off); }
        const float delta = (s - 1.0f) / fmaxf(c, 1.f);
        if (delta <= 1e-7f) break;
        t0 += delta;
      }
      float oacc = 0.f;
      for (int cc = 0; cc < 16; ++cc)
        for (int src = 0; src < 64; ++src) {
          const float z = __shfl(scr2[cc], src);
          const float p = z - t0;
          if (p > 0.f)
            oacc = fmaf(p, Vb[(size_t)(src + 64 * cc) * (kH * kD) + lane], oacc);
        }
      O[obase + lane] = oacc;
    }
  }
}

extern "C" void kernel_launch(void* const* d_in, const int* in_sizes, int n_in,
                              void* d_out, int out_size, void* d_ws, size_t ws_size,
                              hipStream_t stream) {
  (void)in_sizes; (void)n_in; (void)out_size; (void)d_ws; (void)ws_size;
  const float* Q = (const float*)d_in[0];
  const float* K = (const float*)d_in[1];
  const float* V = (const float*)d_in[2];
  float* O = (float*)d_out;
  sparsemax_attn<<<dim3(kB * kH * (kL / LT)), dim3(512), 0, stream>>>(Q, K, V, O);
}

// Round 3
// 406.662 us; speedup vs baseline: 3.6639x; 3.6639x over previous
//
#include <hip/hip_runtime.h>

// Sparsemax attention: B=8, L=1024, S=1024, H=16, E=64, D=64, fp32 in/out.
// r12 = r9 structure (staged-K, 2-barrier/tile, VGPR=64) +
// (1) lists packed to u32: z keeps 13 mantissa bits, low 10 bits hold j
//     (midpoint-restore |512; bias cancels in z-tau). 8B->4B per entry.
// (2) cross-wave filter sharing: each jg-wave publishes its running quarter
//     max to rmax_s[row][jg] EVERY tile (monotone, no barrier needed); the
//     filter threshold is max over all 4 quarters - 1 (true row-max filter,
//     ~40 inserts/row instead of ~75 -- r11's CAP=112 overflowed because the
//     old filter was per-quarter).
// (3) CAP 192->144 with the tighter filter: lists 18KB, total LDS 39680B
//     -> 4 blocks/CU (32 waves, was 16 in r9). launch_bounds kept (512,4);
//     VGPR=64 naturally allows 8 waves/SIMD.

typedef _Float16 f16x8 __attribute__((ext_vector_type(8)));
typedef float    f32x4 __attribute__((ext_vector_type(4)));

constexpr int kB = 8, kL = 1024, kS = 1024, kH = 16, kE = 64, kD = 64;
constexpr int LT   = 32;          // L rows per block (2 query-groups of 16)
constexpr int JT   = 128;         // S cols per staged K tile
constexpr int CAP  = 144;         // candidate capacity per row (mean ~40 now)
constexpr int KMAX = CAP / 16;    // Newton regs per lane (16 lanes per row)

__device__ __forceinline__ float pk2(float a, float b) {
  auto h = __builtin_amdgcn_cvt_pkrtz(a, b);
  return __builtin_bit_cast(float, h);
}

__device__ __forceinline__ float unpack_z(unsigned v) {
  return __uint_as_float((v & ~1023u) | 512u);  // midpoint restore
}

__global__ __launch_bounds__(512, 4)
void sparsemax_attn(const float* __restrict__ Q, const float* __restrict__ K,
                    const float* __restrict__ V, float* __restrict__ O) {
  __shared__ float4   Ksh[JT * 8];      // 16 KB fp16 K tile, swizzled slot^(row&7)
  __shared__ float4   Qsh[LT * 8];      //  4 KB fp16 Q tile (scale folded)
  __shared__ unsigned lists[LT * CAP];  // 18 KB packed (z-hi22 | j10)
  __shared__ int      cnt_s[LT];
  __shared__ float    rmax_s[LT][4];
  __shared__ float    tau_s[LT];

  const int t = threadIdx.x, lane = t & 63, w = t >> 6;
  const int qg = w >> 2, jg = w & 3;       // query-group, j-group
  const int li = lane & 15, g = lane >> 4;
  const int myrow = qg * 16 + li;          // the ONE output row this lane serves

  // XCD-aware remap: round-robin id%8 -> XCD; same-XCD blocks share few bh.
  const int id  = blockIdx.x;              // 4096 blocks
  const int xcd = id & 7, kk = id >> 3;
  const int bh  = xcd * 16 + (kk >> 5);    // 16 bh per XCD, slow-varying
  const int b   = bh >> 4, h = bh & 15;
  const int l0  = (kk & 31) * LT;

  const float* Kbh = K + ((size_t)b * kS * kH + h) * kE;
  const float* Vb  = V + ((size_t)b * kS * kH + h) * kD;

  if (t < LT) cnt_s[t] = 0;
  if (t >= 384 && t < 512) ((float*)rmax_s)[t - 384] = -1e30f;  // init quarters
  if (t < 256) {  // stage Q: 32 rows x 8 slots of 8 halfs
    const int jj = t >> 3, e8 = t & 7;
    const float4* qp =
        (const float4*)(Q + (((size_t)(b * kL + l0 + jj)) * kH + h) * kE + e8 * 8);
    float4 q0 = qp[0], q1 = qp[1];
    q0.x *= .125f; q0.y *= .125f; q0.z *= .125f; q0.w *= .125f;
    q1.x *= .125f; q1.y *= .125f; q1.z *= .125f; q1.w *= .125f;
    Qsh[jj * 8 + (e8 ^ (jj & 7))] =
        make_float4(pk2(q0.x, q0.y), pk2(q0.z, q0.w), pk2(q1.x, q1.y), pk2(q1.z, q1.w));
  }

  float runl = -1e30f;    // per-lane cumulative max over seen scores of myrow
  f16x8 b0, b1;           // cached Q fragments (B operand)

  for (int jt = 0; jt < kS / JT; ++jt) {
    __syncthreads();
    // stage K tile: 128 rows x 64 halfs; 2 units per thread
#pragma unroll
    for (int i = 0; i < 2; ++i) {
      const int idx = t + 512 * i, jj = idx >> 3, e8 = idx & 7;
      const float4* kp =
          (const float4*)(Kbh + (size_t)(jt * JT + jj) * (kH * kE) + e8 * 8);
      const float4 c0 = kp[0], c1 = kp[1];
      Ksh[jj * 8 + (e8 ^ (jj & 7))] =
          make_float4(pk2(c0.x, c0.y), pk2(c0.z, c0.w), pk2(c1.x, c1.y), pk2(c1.z, c1.w));
    }
    __syncthreads();
    if (jt == 0) {  // B-frags: Q[row = myrow][k-chunks g, 4+g] (k-contiguous)
      b0 = __builtin_bit_cast(f16x8, Qsh[myrow * 8 + ((0 + g) ^ (myrow & 7))]);
      b1 = __builtin_bit_cast(f16x8, Qsh[myrow * 8 + ((4 + g) ^ (myrow & 7))]);
    }

    f32x4 acc[2];
    acc[0] = f32x4{0.f, 0.f, 0.f, 0.f};
    acc[1] = f32x4{0.f, 0.f, 0.f, 0.f};
#pragma unroll
    for (int ct = 0; ct < 2; ++ct) {  // A = K rows jl (m dim = j)
      const int jl = jg * 32 + ct * 16 + li;
      const f16x8 a0 = __builtin_bit_cast(f16x8, Ksh[jl * 8 + ((0 + g) ^ (jl & 7))]);
      const f16x8 a1 = __builtin_bit_cast(f16x8, Ksh[jl * 8 + ((4 + g) ^ (jl & 7))]);
      acc[ct] = __builtin_amdgcn_mfma_f32_16x16x32_f16(a0, b0, acc[ct], 0, 0, 0);
      acc[ct] = __builtin_amdgcn_mfma_f32_16x16x32_f16(a1, b1, acc[ct], 0, 0, 0);
    }
    // D[j = jt*128 + jg*32 + ct*16 + g*4 + reg][query = myrow]

    // ---- filter: per-lane max tree + 2-shuffle quarter reduce ----
    const float m01 = fmaxf(fmaxf(acc[0][0], acc[0][1]), fmaxf(acc[0][2], acc[0][3]));
    const float m23 = fmaxf(fmaxf(acc[1][0], acc[1][1]), fmaxf(acc[1][2], acc[1][3]));
    runl = fmaxf(runl, fmaxf(m01, m23));
    float mr = fmaxf(runl, __shfl_xor(runl, 16));
    mr = fmaxf(mr, __shfl_xor(mr, 32));
    // publish this wave's quarter max; read all 4 quarters (stale reads only
    // loosen the threshold -> safe without a barrier; values are monotone).
    if (lane < 16) rmax_s[myrow][jg] = mr;
    float rm = fmaxf(fmaxf(rmax_s[myrow][0], rmax_s[myrow][1]),
                     fmaxf(rmax_s[myrow][2], rmax_s[myrow][3]));
    const float thr = fmaxf(rm, mr) - 1.0f;  // <= rowmax-1 <= tau*: superset
    const int jbase = jt * JT + jg * 32 + g * 4;
#pragma unroll
    for (int ct = 0; ct < 2; ++ct)
#pragma unroll
      for (int r = 0; r < 4; ++r) {
        const float z = acc[ct][r];
        if (z > thr) {
          const int pos = atomicAdd(&cnt_s[myrow], 1);
          if (pos < CAP)
            lists[myrow * CAP + pos] =
                (__float_as_uint(z) & ~1023u) | (unsigned)(jbase + ct * 16 + r);
        }
      }
  }
  __syncthreads();  // lists/cnt/rmax final (last-tile publish precedes this)

  // ---- Newton: wave w owns rows w*4..+3; row w*4+g, 16 lanes each ----
  const int q0 = w * 4;
  {
    const int row = q0 + g;
    const int n   = cnt_s[row];
    const int nc  = min(n, CAP);
    float zr[KMAX];
#pragma unroll
    for (int k = 0; k < KMAX; ++k) {
      const int i = li + 16 * k;
      zr[k] = (i < nc) ? unpack_z(lists[row * CAP + i]) : -1e30f;
    }
    const float M =
        fmaxf(fmaxf(rmax_s[row][0], rmax_s[row][1]), fmaxf(rmax_s[row][2], rmax_s[row][3]));
    float t0 = M - 1.0f;
    for (int it = 0; it < 14; ++it) {
      float s = 0.f, c = 0.f;
#pragma unroll
      for (int k = 0; k < KMAX; ++k) {
        const float d = zr[k] - t0;
        if (d > 0.f) { s += d; c += 1.f; }
      }
      s += __shfl_xor(s, 1); c += __shfl_xor(c, 1);
      s += __shfl_xor(s, 2); c += __shfl_xor(c, 2);
      s += __shfl_xor(s, 4); c += __shfl_xor(c, 4);
      s += __shfl_xor(s, 8); c += __shfl_xor(c, 8);
      const float delta = (s - 1.0f) / fmaxf(c, 1.f);
      t0 += fmaxf(delta, 0.f);
      if (__all(delta <= 1e-6f)) break;
    }
    if (li == 0) tau_s[row] = t0;
  }

  // ---- sparse A*V: 8 candidates concurrent (2 per g), float4 over dims ----
#pragma unroll 1
  for (int r4 = 0; r4 < 4; ++r4) {
    const int row = q0 + r4;
    const int n   = cnt_s[row];
    const size_t obase = (((size_t)(b * kL + l0 + row)) * kH + h) * kD;
    if (n <= CAP) {
      const float tau = tau_s[row];
      const int nc = n;  // n >= 1 always (row max passes its own filter)
      f32x4 o4 = {0.f, 0.f, 0.f, 0.f};
      for (int i = g; i < nc; i += 8) {
        const int   i2 = i + 4;
        const bool  ok2 = (i2 < nc);
        const unsigned e1 = lists[row * CAP + i];
        const unsigned e2 = lists[row * CAP + (ok2 ? i2 : i)];
        const float  p1 = fmaxf(unpack_z(e1) - tau, 0.f);
        const float  p2 = ok2 ? fmaxf(unpack_z(e2) - tau, 0.f) : 0.f;
        const float4 v1 =
            ((const float4*)(Vb + (size_t)(e1 & 1023u) * (kH * kD)))[li];
        const float4 v2 =
            ((const float4*)(Vb + (size_t)(e2 & 1023u) * (kH * kD)))[li];
        o4.x = fmaf(p1, v1.x, fmaf(p2, v2.x, o4.x));
        o4.y = fmaf(p1, v1.y, fmaf(p2, v2.y, o4.y));
        o4.z = fmaf(p1, v1.z, fmaf(p2, v2.z, o4.z));
        o4.w = fmaf(p1, v1.w, fmaf(p2, v2.w, o4.w));
      }
      o4.x += __shfl_xor(o4.x, 16); o4.y += __shfl_xor(o4.y, 16);
      o4.z += __shfl_xor(o4.z, 16); o4.w += __shfl_xor(o4.w, 16);
      o4.x += __shfl_xor(o4.x, 32); o4.y += __shfl_xor(o4.y, 32);
      o4.z += __shfl_xor(o4.z, 32); o4.w += __shfl_xor(o4.w, 32);
      if (lane < 16)
        ((float4*)(O + obase))[li] = make_float4(o4.x, o4.y, o4.z, o4.w);
    } else {
      // ---- cold exact fallback (list overflow): dense recompute ----
      float scr2[16];
      for (int cc = 0; cc < 16; ++cc) {
        const int j = lane + 64 * cc;
        const float* kr = Kbh + (size_t)j * (kH * kE);
        float zz = 0.f;
        for (int e8 = 0; e8 < 8; ++e8) {
          const f16x8 qh = __builtin_bit_cast(f16x8, Qsh[row * 8 + (e8 ^ (row & 7))]);
          const float4* kp = (const float4*)(kr + e8 * 8);
          const float4 c0 = kp[0], c1 = kp[1];
          zz += (float)qh[0] * c0.x + (float)qh[1] * c0.y + (float)qh[2] * c0.z +
                (float)qh[3] * c0.w + (float)qh[4] * c1.x + (float)qh[5] * c1.y +
                (float)qh[6] * c1.z + (float)qh[7] * c1.w;
        }
        scr2[cc] = zz;
      }
      const float M2 =
          fmaxf(fmaxf(rmax_s[row][0], rmax_s[row][1]), fmaxf(rmax_s[row][2], rmax_s[row][3]));
      float t0 = M2 - 1.0f;
      for (int it = 0; it < 48; ++it) {
        float s = 0.f, c = 0.f;
        for (int cc = 0; cc < 16; ++cc) {
          const float d = scr2[cc] - t0;
          if (d > 0.f) { s += d; c += 1.f; }
        }
        for (int off = 32; off; off >>= 1) { s += __shfl_xor(s, off); c += __shfl_xor(c, off); }
        const float delta = (s - 1.0f) / fmaxf(c, 1.f);
        if (delta <= 1e-7f) break;
        t0 += delta;
      }
      float oacc = 0.f;
      for (int cc = 0; cc < 16; ++cc)
        for (int src = 0; src < 64; ++src) {
          const float z = __shfl(scr2[cc], src);
          const float p = z - t0;
          if (p > 0.f)
            oacc = fmaf(p, Vb[(size_t)(src + 64 * cc) * (kH * kD) + lane], oacc);
        }
      O[obase + lane] = oacc;
    }
  }
}

extern "C" void kernel_launch(void* const* d_in, const int* in_sizes, int n_in,
                              void* d_out, int out_size, void* d_ws, size_t ws_size,
                              hipStream_t stream) {
  (void)in_sizes; (void)n_in; (void)out_size; (void)d_ws; (void)ws_size;
  const float* Q = (const float*)d_in[0];
  const float* K = (const float*)d_in[1];
  const float* V = (const float*)d_in[2];
  float* O = (float*)d_out;
  sparsemax_attn<<<dim3(kB * kH * (kL / LT)), dim3(512), 0, stream>>>(Q, K, V, O);
}